// Round 2
// baseline (1737.032 us; speedup 1.0000x reference)
//
#include <hip/hip_runtime.h>

#define NN 100000
#define EE 1600000
#define DD 128
#define NL 3
#define NQ 3
#define KK 16
#define PADK 132          // padded codebook row (floats), 16B-aligned
#define FUSED_BLOCKS 25000
#define LPART_COUNT (NL * FUSED_BLOCKS)

// ---- workspace layout (bytes) ----
static constexpr size_t OFF_AGG   = 0;          // N*D f32       = 51,200,000
static constexpr size_t OFF_CSR   = 51200000;   // E   i32       =  6,400,000
static constexpr size_t OFF_CBN   = 57600000;   // 3*3*16*132 f32=    304,128
static constexpr size_t OFF_NORM  = 57904128;   // N   f32       =    400,000
static constexpr size_t OFF_DEG   = 58304128;   // N   i32       =    400,000
static constexpr size_t OFF_CUR   = 58704128;   // N   i32       =    400,000
static constexpr size_t OFF_RS    = 59104128;   // (N+1) i32     =    400,004
static constexpr size_t OFF_BSUM  = 59504640;   // 128 i32
static constexpr size_t OFF_LPART = 59505152;   // NL*25000 f32  =    300,000
static constexpr size_t WS_NEEDED = 59805152;

// ---------- CSR build ----------
__global__ __launch_bounds__(256) void k_count(const int* __restrict__ erow,
                                               int* __restrict__ deg) {
    int e = blockIdx.x * 256 + threadIdx.x;
    if (e < EE) atomicAdd(&deg[erow[e]], 1);
}

__global__ __launch_bounds__(1024) void k_scan1(const int* __restrict__ deg,
                                                int* __restrict__ rs,
                                                int* __restrict__ bsum) {
    __shared__ int s[1024];
    int tid = threadIdx.x;
    int idx = blockIdx.x * 1024 + tid;
    int v = (idx < NN) ? deg[idx] : 0;
    s[tid] = v;
    __syncthreads();
    for (int o = 1; o < 1024; o <<= 1) {
        int t2 = s[tid];
        if (tid >= o) t2 += s[tid - o];
        __syncthreads();
        s[tid] = t2;
        __syncthreads();
    }
    if (idx < NN) rs[idx] = s[tid] - v;       // exclusive
    if (tid == 1023) bsum[blockIdx.x] = s[1023];
}

__global__ __launch_bounds__(128) void k_scan2(int* __restrict__ bsum, int nb) {
    __shared__ int s[128];
    int tid = threadIdx.x;
    int v = (tid < nb) ? bsum[tid] : 0;
    s[tid] = v;
    __syncthreads();
    for (int o = 1; o < 128; o <<= 1) {
        int t2 = s[tid];
        if (tid >= o) t2 += s[tid - o];
        __syncthreads();
        s[tid] = t2;
        __syncthreads();
    }
    if (tid < nb) bsum[tid] = s[tid] - v;     // exclusive
}

__global__ __launch_bounds__(1024) void k_scan3(const int* __restrict__ deg,
                                                int* __restrict__ rs,
                                                const int* __restrict__ bsum,
                                                float* __restrict__ normf) {
    int idx = blockIdx.x * 1024 + threadIdx.x;
    if (idx < NN) {
        rs[idx] += bsum[blockIdx.x];
        normf[idx] = rsqrtf(1.0f + (float)deg[idx]);
    }
    if (idx == 0) rs[NN] = EE;
}

__global__ __launch_bounds__(256) void k_fill(const int* __restrict__ erow,
                                              const int* __restrict__ ecol,
                                              const int* __restrict__ rs,
                                              int* __restrict__ cursor,
                                              int* __restrict__ csr) {
    int e = blockIdx.x * 256 + threadIdx.x;
    if (e < EE) {
        int r = erow[e];
        int p = atomicAdd(&cursor[r], 1);
        csr[rs[r] + p] = ecol[e];
    }
}

// ---------- canonicalize neighbor order (determinism across replays) ----------
// Atomic fill order varies run-to-run; FP summation order must not. Sort each
// row's slice ascending by col. Equal cols are bitwise-identical addends, so
// their relative order cannot change the sum.
__global__ __launch_bounds__(256) void k_sortrow(const int* __restrict__ rs,
                                                 int* __restrict__ csr) {
    int r = blockIdx.x * 256 + threadIdx.x;
    if (r >= NN) return;
    int s0 = rs[r], e0 = rs[r + 1];
    for (int i = s0 + 1; i < e0; ++i) {
        int v = csr[i];
        int j = i - 1;
        while (j >= s0 && csr[j] > v) { csr[j + 1] = csr[j]; --j; }
        csr[j + 1] = v;
    }
}

// ---------- codebook normalize (144 rows of 128) ----------
__global__ __launch_bounds__(128) void k_cbnorm(const float* __restrict__ cb,
                                                float* __restrict__ cbn) {
    __shared__ float s[128];
    int row = blockIdx.x;                 // (layer*3+q)*16 + k
    int tid = threadIdx.x;
    float v = cb[row * DD + tid];
    s[tid] = v * v;
    __syncthreads();
    for (int o = 64; o > 0; o >>= 1) {
        if (tid < o) s[tid] += s[tid + o];
        __syncthreads();
    }
    float inv = 1.0f / (sqrtf(s[0]) + 1e-12f);
    cbn[(size_t)row * PADK + tid] = v * inv;
}

// ---------- input linear: h = x @ w + b ----------
__global__ __launch_bounds__(256) void k_gemm(const float* __restrict__ x,
                                              const float* __restrict__ w,
                                              const float* __restrict__ bias,
                                              float* __restrict__ h) {
    __shared__ float xs[8][DD];
    int tid = threadIdx.x;
    int rbase = blockIdx.x * 8;
    {
        int rr = tid >> 5, cc = (tid & 31) * 4;
        *(float4*)&xs[rr][cc] = *(const float4*)&x[(size_t)(rbase + rr) * DD + cc];
    }
    __syncthreads();
    int rg = tid >> 5;            // row within tile
    int cg = (tid & 31) * 4;      // col group
    float4 acc = {0.f, 0.f, 0.f, 0.f};
#pragma unroll 4
    for (int k = 0; k < DD; ++k) {
        float xv = xs[rg][k];
        float4 wv = *(const float4*)&w[k * DD + cg];
        acc.x += xv * wv.x; acc.y += xv * wv.y;
        acc.z += xv * wv.z; acc.w += xv * wv.w;
    }
    float4 bv = *(const float4*)&bias[cg];
    acc.x += bv.x; acc.y += bv.y; acc.z += bv.z; acc.w += bv.w;
    *(float4*)&h[(size_t)(rbase + rg) * DD + cg] = acc;
}

// ---------- SpMM: agg[r] = sum_{c in neigh(r)} norm[c]*h[c] ----------
__global__ __launch_bounds__(256) void k_spmm(const float* __restrict__ h,
                                              const float* __restrict__ normf,
                                              const int* __restrict__ rs,
                                              const int* __restrict__ csr,
                                              float* __restrict__ agg) {
    int half = threadIdx.x >> 7;
    int t = threadIdx.x & 127;
    int r = blockIdx.x * 2 + half;
    int s0 = rs[r], e0 = rs[r + 1];
    float acc = 0.f;
    for (int j = s0; j < e0; ++j) {
        int c = csr[j];
        acc += normf[c] * h[(size_t)c * DD + t];
    }
    agg[(size_t)r * DD + t] = acc;
}

// ---------- fused: x1 = norm*(agg + norm*h); residual VQ; h += x1 ----------
__global__ __launch_bounds__(256) void k_fused(const float* __restrict__ agg,
                                               float* __restrict__ h,
                                               const float* __restrict__ normf,
                                               const float* __restrict__ cbn_layer,
                                               float* __restrict__ idsf,
                                               float* __restrict__ lpart,
                                               int layer) {
    __shared__ float cb_s[NQ * KK * PADK];   // 25,344 B
    __shared__ float resid_s[4][DD];
    __shared__ float wsum[4];
    int tid = threadIdx.x;

    // copy this layer's normalized codebooks (float4)
    {
        const float4* src = (const float4*)cbn_layer;
        float4* dst = (float4*)cb_s;
        for (int i = tid; i < NQ * KK * PADK / 4; i += 256) dst[i] = src[i];
    }
    __syncthreads();

    int w = tid >> 6;      // wave id = row within block
    int l = tid & 63;      // lane
    int r = blockIdx.x * 4 + w;

    float nr = normf[r];
    float h0 = h[(size_t)r * DD + l];
    float h1 = h[(size_t)r * DD + l + 64];
    float a0 = agg[(size_t)r * DD + l];
    float a1 = agg[(size_t)r * DD + l + 64];
    float x0 = nr * (a0 + nr * h0);
    float x1 = nr * (a1 + nr * h1);
    float r0 = x0, r1 = x1;
    float lsum = 0.f;

    int kq = l >> 2;       // codebook entry this lane helps with
    int sq = l & 3;        // 32-dim slice

    for (int q = 0; q < NQ; ++q) {
        resid_s[w][l] = r0;
        resid_s[w][l + 64] = r1;
        __syncthreads();

        const float* cbq = &cb_s[(q * KK + kq) * PADK];
        const float* rsd = resid_s[w];
        float pd = 0.f;
#pragma unroll
        for (int i = 0; i < 8; ++i) {
            float4 cv = *(const float4*)&cbq[sq * 32 + i * 4];
            float4 rv = *(const float4*)&rsd[sq * 32 + i * 4];
            pd += cv.x * rv.x + cv.y * rv.y + cv.z * rv.z + cv.w * rv.w;
        }
        pd += __shfl_xor(pd, 1);
        pd += __shfl_xor(pd, 2);     // full dot(resid, cbn[kq]) on each lane of group

        float best = pd;
        int bk = kq;
        for (int m = 4; m < 64; m <<= 1) {
            float ov = __shfl_xor(best, m);
            int oi = __shfl_xor(bk, m);
            if (ov > best || (ov == best && oi < bk)) { best = ov; bk = oi; }
        }
        // bk = argmax (min index on tie), agreed by all lanes

        const float* cbk = &cb_s[(q * KK + bk) * PADK];
        r0 -= cbk[l];
        r1 -= cbk[l + 64];
        lsum += r0 * r0 + r1 * r1;

        if (l == 0) idsf[(size_t)r * (NL * NQ) + layer * NQ + q] = (float)bk;
        __syncthreads();
    }

    // h += x1
    h[(size_t)r * DD + l] = x0 + h0;
    h[(size_t)r * DD + l + 64] = x1 + h1;

    // block loss partial (deterministic)
#pragma unroll
    for (int m = 1; m < 64; m <<= 1) lsum += __shfl_xor(lsum, m);
    if (l == 0) wsum[w] = lsum;
    __syncthreads();
    if (tid == 0) {
        float tot = wsum[0] + wsum[1] + wsum[2] + wsum[3];
        lpart[layer * FUSED_BLOCKS + blockIdx.x] = tot * (0.25f / (float)(NN * DD));
    }
}

__global__ __launch_bounds__(256) void k_loss_reduce(const float* __restrict__ part,
                                                     float* __restrict__ out_loss) {
    __shared__ float s[256];
    float a = 0.f;
    for (int i = threadIdx.x; i < LPART_COUNT; i += 256) a += part[i];
    s[threadIdx.x] = a;
    __syncthreads();
    for (int o = 128; o > 0; o >>= 1) {
        if (threadIdx.x < o) s[threadIdx.x] += s[threadIdx.x + o];
        __syncthreads();
    }
    if (threadIdx.x == 0) out_loss[0] = s[0];
}

extern "C" void kernel_launch(void* const* d_in, const int* in_sizes, int n_in,
                              void* d_out, int out_size, void* d_ws, size_t ws_size,
                              hipStream_t stream) {
    if (ws_size < WS_NEEDED) return;

    const float* x    = (const float*)d_in[0];
    const float* w_in = (const float*)d_in[1];
    const float* b_in = (const float*)d_in[2];
    const float* cbs  = (const float*)d_in[3];
    const int*   erow = (const int*)d_in[4];
    const int*   ecol = (const int*)d_in[5];

    float* out  = (float*)d_out;
    float* hbuf = out;                                   // [N][D] working h = output 0
    float* loss = out + (size_t)NN * DD;                 // scalar output 1
    float* idsf = out + (size_t)NN * DD + 1;             // [N][9] output 2 (as float)

    char* ws = (char*)d_ws;
    float* agg    = (float*)(ws + OFF_AGG);
    int*   csr    = (int*)(ws + OFF_CSR);
    float* cbn    = (float*)(ws + OFF_CBN);
    float* normf  = (float*)(ws + OFF_NORM);
    int*   deg    = (int*)(ws + OFF_DEG);
    int*   cursor = (int*)(ws + OFF_CUR);
    int*   rs     = (int*)(ws + OFF_RS);
    int*   bsum   = (int*)(ws + OFF_BSUM);
    float* lpart  = (float*)(ws + OFF_LPART);

    // zero deg + cursor (contiguous)
    hipMemsetAsync(ws + OFF_DEG, 0, 800000, stream);

    const int NB_E  = (EE + 255) / 256;      // 6250
    const int NB_SC = (NN + 1023) / 1024;    // 98
    const int NB_N  = (NN + 255) / 256;      // 391

    k_count<<<NB_E, 256, 0, stream>>>(erow, deg);
    k_scan1<<<NB_SC, 1024, 0, stream>>>(deg, rs, bsum);
    k_scan2<<<1, 128, 0, stream>>>(bsum, NB_SC);
    k_scan3<<<NB_SC, 1024, 0, stream>>>(deg, rs, bsum, normf);
    k_fill<<<NB_E, 256, 0, stream>>>(erow, ecol, rs, cursor, csr);
    k_sortrow<<<NB_N, 256, 0, stream>>>(rs, csr);

    k_cbnorm<<<NL * NQ * KK, 128, 0, stream>>>(cbs, cbn);
    k_gemm<<<NN / 8, 256, 0, stream>>>(x, w_in, b_in, hbuf);

    for (int layer = 0; layer < NL; ++layer) {
        k_spmm<<<NN / 2, 256, 0, stream>>>(hbuf, normf, rs, csr, agg);
        k_fused<<<FUSED_BLOCKS, 256, 0, stream>>>(agg, hbuf, normf,
                                                  cbn + (size_t)layer * NQ * KK * PADK,
                                                  idsf, lpart, layer);
    }

    k_loss_reduce<<<1, 256, 0, stream>>>(lpart, loss);
}

// Round 4
// 1136.070 us; speedup vs baseline: 1.5290x; 1.5290x over previous
//
#include <hip/hip_runtime.h>

#define NN 100000
#define EE 1600000
#define DD 128
#define NL 3
#define NQ 3
#define KK 16
#define PADK 132          // padded codebook row (floats), 16B-aligned
#define ROWS_PER_FBLOCK 32
#define FUSED_BLOCKS (NN / ROWS_PER_FBLOCK)      // 3125
#define LPART_COUNT (NL * FUSED_BLOCKS)

// ---- workspace layout (bytes) ----
static constexpr size_t OFF_AGG   = 0;          // N*D f32       = 51,200,000
static constexpr size_t OFF_CSR   = 51200000;   // E   i32       =  6,400,000
static constexpr size_t OFF_CBN   = 57600000;   // 3*3*16*132 f32=    304,128
static constexpr size_t OFF_NORM  = 57904128;   // N   f32       =    400,000
static constexpr size_t OFF_DEG   = 58304128;   // N   i32       =    400,000
static constexpr size_t OFF_CUR   = 58704128;   // N   i32       =    400,000
static constexpr size_t OFF_RS    = 59104128;   // (N+1) i32     =    400,004
static constexpr size_t OFF_BSUM  = 59504640;   // 128 i32
static constexpr size_t OFF_LPART = 59505152;   // NL*3125 f32
static constexpr size_t WS_NEEDED = 59805152;

// ---------- CSR build ----------
__global__ __launch_bounds__(256) void k_count(const int* __restrict__ erow,
                                               int* __restrict__ deg) {
    int e = blockIdx.x * 256 + threadIdx.x;
    if (e < EE) atomicAdd(&deg[erow[e]], 1);
}

__global__ __launch_bounds__(1024) void k_scan1(const int* __restrict__ deg,
                                                int* __restrict__ rs,
                                                int* __restrict__ bsum) {
    __shared__ int s[1024];
    int tid = threadIdx.x;
    int idx = blockIdx.x * 1024 + tid;
    int v = (idx < NN) ? deg[idx] : 0;
    s[tid] = v;
    __syncthreads();
    for (int o = 1; o < 1024; o <<= 1) {
        int t2 = s[tid];
        if (tid >= o) t2 += s[tid - o];
        __syncthreads();
        s[tid] = t2;
        __syncthreads();
    }
    if (idx < NN) rs[idx] = s[tid] - v;       // exclusive
    if (tid == 1023) bsum[blockIdx.x] = s[1023];
}

__global__ __launch_bounds__(128) void k_scan2(int* __restrict__ bsum, int nb) {
    __shared__ int s[128];
    int tid = threadIdx.x;
    int v = (tid < nb) ? bsum[tid] : 0;
    s[tid] = v;
    __syncthreads();
    for (int o = 1; o < 128; o <<= 1) {
        int t2 = s[tid];
        if (tid >= o) t2 += s[tid - o];
        __syncthreads();
        s[tid] = t2;
        __syncthreads();
    }
    if (tid < nb) bsum[tid] = s[tid] - v;     // exclusive
}

__global__ __launch_bounds__(1024) void k_scan3(const int* __restrict__ deg,
                                                int* __restrict__ rs,
                                                const int* __restrict__ bsum,
                                                float* __restrict__ normf) {
    int idx = blockIdx.x * 1024 + threadIdx.x;
    if (idx < NN) {
        rs[idx] += bsum[blockIdx.x];
        normf[idx] = rsqrtf(1.0f + (float)deg[idx]);
    }
    if (idx == 0) rs[NN] = EE;
}

__global__ __launch_bounds__(256) void k_fill(const int* __restrict__ erow,
                                              const int* __restrict__ ecol,
                                              const int* __restrict__ rs,
                                              int* __restrict__ cursor,
                                              int* __restrict__ csr) {
    int e = blockIdx.x * 256 + threadIdx.x;
    if (e < EE) {
        int r = erow[e];
        int p = atomicAdd(&cursor[r], 1);
        csr[rs[r] + p] = ecol[e];
    }
}

// ---------- canonicalize neighbor order (determinism across replays) ----------
// Wave-per-row rank sort: final content is ascending by col, independent of
// the nondeterministic atomic fill order (ties hold identical values).
__global__ __launch_bounds__(256) void k_sortwave(const int* __restrict__ rs,
                                                  int* __restrict__ csr) {
    int wid = (blockIdx.x * 256 + threadIdx.x) >> 6;   // one wave per row
    int l = threadIdx.x & 63;
    if (wid >= NN) return;
    int s0 = rs[wid], e0 = rs[wid + 1];
    int deg = e0 - s0;
    if (deg <= 1) return;
    if (deg <= 64) {
        int v = (l < deg) ? csr[s0 + l] : 0x7fffffff;
        int rank = 0;
#pragma unroll 8
        for (int m = 0; m < 64; ++m) {
            int vm = __shfl(v, m);
            bool less = (vm < v) || (vm == v && m < l);
            rank += (m < deg && less) ? 1 : 0;
        }
        if (l < deg) csr[s0 + rank] = v;
    } else if (l == 0) {                    // vanishingly rare fallback
        for (int i = s0 + 1; i < e0; ++i) {
            int v = csr[i];
            int j = i - 1;
            while (j >= s0 && csr[j] > v) { csr[j + 1] = csr[j]; --j; }
            csr[j + 1] = v;
        }
    }
}

// ---------- codebook normalize (144 rows of 128) ----------
__global__ __launch_bounds__(128) void k_cbnorm(const float* __restrict__ cb,
                                                float* __restrict__ cbn) {
    __shared__ float s[128];
    int row = blockIdx.x;                 // (layer*3+q)*16 + k
    int tid = threadIdx.x;
    float v = cb[row * DD + tid];
    s[tid] = v * v;
    __syncthreads();
    for (int o = 64; o > 0; o >>= 1) {
        if (tid < o) s[tid] += s[tid + o];
        __syncthreads();
    }
    float inv = 1.0f / (sqrtf(s[0]) + 1e-12f);
    cbn[(size_t)row * PADK + tid] = v * inv;
}

// ---------- input linear: h = x @ w + b ----------
__global__ __launch_bounds__(256) void k_gemm(const float* __restrict__ x,
                                              const float* __restrict__ w,
                                              const float* __restrict__ bias,
                                              float* __restrict__ h) {
    __shared__ float xs[8][DD];
    int tid = threadIdx.x;
    int rbase = blockIdx.x * 8;
    {
        int rr = tid >> 5, cc = (tid & 31) * 4;
        *(float4*)&xs[rr][cc] = *(const float4*)&x[(size_t)(rbase + rr) * DD + cc];
    }
    __syncthreads();
    int rg = tid >> 5;            // row within tile
    int cg = (tid & 31) * 4;      // col group
    float4 acc = {0.f, 0.f, 0.f, 0.f};
#pragma unroll 4
    for (int k = 0; k < DD; ++k) {
        float xv = xs[rg][k];
        float4 wv = *(const float4*)&w[k * DD + cg];
        acc.x += xv * wv.x; acc.y += xv * wv.y;
        acc.z += xv * wv.z; acc.w += xv * wv.w;
    }
    float4 bv = *(const float4*)&bias[cg];
    acc.x += bv.x; acc.y += bv.y; acc.z += bv.z; acc.w += bv.w;
    *(float4*)&h[(size_t)(rbase + rg) * DD + cg] = acc;
}

// ---------- SpMM: agg[r] = sum_{c in neigh(r)} norm[c]*h[c] ----------
// 32 lanes per row (float4 each), 8 rows per 256-block. Unroll-by-4 keeps 4
// gathers in flight; per-dim adds stay in ascending-j order as separate +=
// statements -> bit-identical to the sequential round-2 accumulation.
__global__ __launch_bounds__(256) void k_spmm(const float* __restrict__ h,
                                              const float* __restrict__ normf,
                                              const int* __restrict__ rs,
                                              const int* __restrict__ csr,
                                              float* __restrict__ agg) {
    int lane = threadIdx.x & 31;
    int slot = threadIdx.x >> 5;
    int r = blockIdx.x * 8 + slot;
    int s0 = rs[r], e0 = rs[r + 1];
    int off = lane << 2;

    float ax = 0.f, ay = 0.f, az = 0.f, aw = 0.f;
    int j = s0;
    for (; j + 4 <= e0; j += 4) {
        int c0 = csr[j], c1 = csr[j + 1], c2 = csr[j + 2], c3 = csr[j + 3];
        float n0 = normf[c0], n1 = normf[c1], n2 = normf[c2], n3 = normf[c3];
        float4 v0 = *(const float4*)&h[(size_t)c0 * DD + off];
        float4 v1 = *(const float4*)&h[(size_t)c1 * DD + off];
        float4 v2 = *(const float4*)&h[(size_t)c2 * DD + off];
        float4 v3 = *(const float4*)&h[(size_t)c3 * DD + off];
        ax += n0 * v0.x; ax += n1 * v1.x; ax += n2 * v2.x; ax += n3 * v3.x;
        ay += n0 * v0.y; ay += n1 * v1.y; ay += n2 * v2.y; ay += n3 * v3.y;
        az += n0 * v0.z; az += n1 * v1.z; az += n2 * v2.z; az += n3 * v3.z;
        aw += n0 * v0.w; aw += n1 * v1.w; aw += n2 * v2.w; aw += n3 * v3.w;
    }
    for (; j < e0; ++j) {
        int c = csr[j];
        float ns = normf[c];
        float4 v = *(const float4*)&h[(size_t)c * DD + off];
        ax += ns * v.x;
        ay += ns * v.y;
        az += ns * v.z;
        aw += ns * v.w;
    }
    float4 o = {ax, ay, az, aw};
    *(float4*)&agg[(size_t)r * DD + off] = o;
}

// ---------- fused: x1 = norm*(agg + norm*h); residual VQ; h += x1 ----------
// 32 rows per block (4 at a time, one per wave); codebook staged once.
__global__ __launch_bounds__(256) void k_fused(const float* __restrict__ agg,
                                               float* __restrict__ h,
                                               const float* __restrict__ normf,
                                               const float* __restrict__ cbn_layer,
                                               float* __restrict__ idsf,
                                               float* __restrict__ lpart,
                                               int layer) {
    __shared__ float cb_s[NQ * KK * PADK];   // 25,344 B
    __shared__ float resid_s[4][DD];
    __shared__ float wsum[4];
    int tid = threadIdx.x;

    {
        const float4* src = (const float4*)cbn_layer;
        float4* dst = (float4*)cb_s;
        for (int i = tid; i < NQ * KK * PADK / 4; i += 256) dst[i] = src[i];
    }
    __syncthreads();

    int w = tid >> 6;      // wave id
    int l = tid & 63;      // lane
    int kq = l >> 2;       // codebook entry this lane helps with
    int sq = l & 3;        // 32-dim slice
    float lsum = 0.f;

    for (int it = 0; it < ROWS_PER_FBLOCK / 4; ++it) {
        int r = blockIdx.x * ROWS_PER_FBLOCK + it * 4 + w;

        float nr = normf[r];
        float2 hv = *(const float2*)&h[(size_t)r * DD + 2 * l];
        float2 av = *(const float2*)&agg[(size_t)r * DD + 2 * l];
        float x0 = nr * (av.x + nr * hv.x);
        float x1 = nr * (av.y + nr * hv.y);
        float r0 = x0, r1 = x1;

        for (int q = 0; q < NQ; ++q) {
            *(float2*)&resid_s[w][2 * l] = make_float2(r0, r1);
            __syncthreads();

            const float* cbq = &cb_s[(q * KK + kq) * PADK];
            const float* rsd = resid_s[w];
            float pd = 0.f;
#pragma unroll
            for (int i = 0; i < 8; ++i) {
                float4 cv = *(const float4*)&cbq[sq * 32 + i * 4];
                float4 rv = *(const float4*)&rsd[sq * 32 + i * 4];
                pd += cv.x * rv.x + cv.y * rv.y + cv.z * rv.z + cv.w * rv.w;
            }
            pd += __shfl_xor(pd, 1);
            pd += __shfl_xor(pd, 2);   // full dot(resid, cbn[kq]) in each quad

            float best = pd;
            int bk = kq;
            for (int m = 4; m < 64; m <<= 1) {
                float ov = __shfl_xor(best, m);
                int oi = __shfl_xor(bk, m);
                if (ov > best || (ov == best && oi < bk)) { best = ov; bk = oi; }
            }
            // bk = argmax (min index on tie), agreed by all lanes

            const float* cbk = &cb_s[(q * KK + bk) * PADK];
            float2 cv = *(const float2*)&cbk[2 * l];
            r0 -= cv.x;
            r1 -= cv.y;
            lsum += r0 * r0 + r1 * r1;

            if (l == 0) idsf[(size_t)r * (NL * NQ) + layer * NQ + q] = (float)bk;
            __syncthreads();
        }

        *(float2*)&h[(size_t)r * DD + 2 * l] = make_float2(x0 + hv.x, x1 + hv.y);
    }

    // block loss partial (deterministic)
#pragma unroll
    for (int m = 1; m < 64; m <<= 1) lsum += __shfl_xor(lsum, m);
    if (l == 0) wsum[w] = lsum;
    __syncthreads();
    if (tid == 0) {
        float tot = wsum[0] + wsum[1] + wsum[2] + wsum[3];
        lpart[layer * FUSED_BLOCKS + blockIdx.x] = tot * (0.25f / (float)(NN * DD));
    }
}

__global__ __launch_bounds__(256) void k_loss_reduce(const float* __restrict__ part,
                                                     float* __restrict__ out_loss) {
    __shared__ float s[256];
    float a = 0.f;
    for (int i = threadIdx.x; i < LPART_COUNT; i += 256) a += part[i];
    s[threadIdx.x] = a;
    __syncthreads();
    for (int o = 128; o > 0; o >>= 1) {
        if (threadIdx.x < o) s[threadIdx.x] += s[threadIdx.x + o];
        __syncthreads();
    }
    if (threadIdx.x == 0) out_loss[0] = s[0];
}

extern "C" void kernel_launch(void* const* d_in, const int* in_sizes, int n_in,
                              void* d_out, int out_size, void* d_ws, size_t ws_size,
                              hipStream_t stream) {
    if (ws_size < WS_NEEDED) return;

    const float* x    = (const float*)d_in[0];
    const float* w_in = (const float*)d_in[1];
    const float* b_in = (const float*)d_in[2];
    const float* cbs  = (const float*)d_in[3];
    const int*   erow = (const int*)d_in[4];
    const int*   ecol = (const int*)d_in[5];

    float* out  = (float*)d_out;
    float* hbuf = out;                                   // [N][D] working h = output 0
    float* loss = out + (size_t)NN * DD;                 // scalar output 1
    float* idsf = out + (size_t)NN * DD + 1;             // [N][9] output 2 (as float)

    char* ws = (char*)d_ws;
    float* agg    = (float*)(ws + OFF_AGG);
    int*   csr    = (int*)(ws + OFF_CSR);
    float* cbn    = (float*)(ws + OFF_CBN);
    float* normf  = (float*)(ws + OFF_NORM);
    int*   deg    = (int*)(ws + OFF_DEG);
    int*   cursor = (int*)(ws + OFF_CUR);
    int*   rs     = (int*)(ws + OFF_RS);
    int*   bsum   = (int*)(ws + OFF_BSUM);
    float* lpart  = (float*)(ws + OFF_LPART);

    // zero deg + cursor (contiguous)
    hipMemsetAsync(ws + OFF_DEG, 0, 800000, stream);

    const int NB_E  = (EE + 255) / 256;      // 6250
    const int NB_SC = (NN + 1023) / 1024;    // 98
    const int NB_W  = (NN + 3) / 4;          // 25000 (4 waves/block)

    k_count<<<NB_E, 256, 0, stream>>>(erow, deg);
    k_scan1<<<NB_SC, 1024, 0, stream>>>(deg, rs, bsum);
    k_scan2<<<1, 128, 0, stream>>>(bsum, NB_SC);
    k_scan3<<<NB_SC, 1024, 0, stream>>>(deg, rs, bsum, normf);
    k_fill<<<NB_E, 256, 0, stream>>>(erow, ecol, rs, cursor, csr);
    k_sortwave<<<NB_W, 256, 0, stream>>>(rs, csr);

    k_cbnorm<<<NL * NQ * KK, 128, 0, stream>>>(cbs, cbn);
    k_gemm<<<NN / 8, 256, 0, stream>>>(x, w_in, b_in, hbuf);

    for (int layer = 0; layer < NL; ++layer) {
        k_spmm<<<NN / 8, 256, 0, stream>>>(hbuf, normf, rs, csr, agg);
        k_fused<<<FUSED_BLOCKS, 256, 0, stream>>>(agg, hbuf, normf,
                                                  cbn + (size_t)layer * NQ * KK * PADK,
                                                  idsf, lpart, layer);
    }

    k_loss_reduce<<<1, 256, 0, stream>>>(lpart, loss);
}

// Round 6
// 1020.631 us; speedup vs baseline: 1.7019x; 1.1131x over previous
//
#include <hip/hip_runtime.h>

#define NN 100000
#define EE 1600000
#define DD 128
#define NL 3
#define NQ 3
#define KK 16
#define PADK 132          // padded codebook row (floats), 16B-aligned
#define ROWS_PER_FBLOCK 32
#define FUSED_BLOCKS (NN / ROWS_PER_FBLOCK)      // 3125
#define LPART_COUNT (NL * FUSED_BLOCKS)

// ---- workspace layout (bytes) ----
static constexpr size_t OFF_AGG   = 0;          // N*D f32       = 51,200,000
static constexpr size_t OFF_CSR   = 51200000;   // E   i32       =  6,400,000
static constexpr size_t OFF_CBN   = 57600000;   // 3*3*16*132 f32=    304,128
static constexpr size_t OFF_NORM  = 57904128;   // N   f32       =    400,000
static constexpr size_t OFF_DEG   = 58304128;   // N   i32       =    400,000
static constexpr size_t OFF_CUR   = 58704128;   // N   i32       =    400,000
static constexpr size_t OFF_RS    = 59104128;   // (N+1) i32     =    400,004
static constexpr size_t OFF_BSUM  = 59504640;   // 128 i32
static constexpr size_t OFF_LPART = 59505152;   // NL*3125 f32
static constexpr size_t WS_NEEDED = 59805152;

// ---------- CSR build ----------
__global__ __launch_bounds__(256) void k_count(const int* __restrict__ erow,
                                               int* __restrict__ deg) {
    int e = blockIdx.x * 256 + threadIdx.x;
    if (e < EE) atomicAdd(&deg[erow[e]], 1);
}

__global__ __launch_bounds__(1024) void k_scan1(const int* __restrict__ deg,
                                                int* __restrict__ rs,
                                                int* __restrict__ bsum) {
    __shared__ int s[1024];
    int tid = threadIdx.x;
    int idx = blockIdx.x * 1024 + tid;
    int v = (idx < NN) ? deg[idx] : 0;
    s[tid] = v;
    __syncthreads();
    for (int o = 1; o < 1024; o <<= 1) {
        int t2 = s[tid];
        if (tid >= o) t2 += s[tid - o];
        __syncthreads();
        s[tid] = t2;
        __syncthreads();
    }
    if (idx < NN) rs[idx] = s[tid] - v;       // exclusive
    if (tid == 1023) bsum[blockIdx.x] = s[1023];
}

__global__ __launch_bounds__(128) void k_scan2(int* __restrict__ bsum, int nb) {
    __shared__ int s[128];
    int tid = threadIdx.x;
    int v = (tid < nb) ? bsum[tid] : 0;
    s[tid] = v;
    __syncthreads();
    for (int o = 1; o < 128; o <<= 1) {
        int t2 = s[tid];
        if (tid >= o) t2 += s[tid - o];
        __syncthreads();
        s[tid] = t2;
        __syncthreads();
    }
    if (tid < nb) bsum[tid] = s[tid] - v;     // exclusive
}

__global__ __launch_bounds__(1024) void k_scan3(const int* __restrict__ deg,
                                                int* __restrict__ rs,
                                                const int* __restrict__ bsum,
                                                float* __restrict__ normf) {
    int idx = blockIdx.x * 1024 + threadIdx.x;
    if (idx < NN) {
        rs[idx] += bsum[blockIdx.x];
        normf[idx] = rsqrtf(1.0f + (float)deg[idx]);
    }
    if (idx == 0) rs[NN] = EE;
}

__global__ __launch_bounds__(256) void k_fill(const int* __restrict__ erow,
                                              const int* __restrict__ ecol,
                                              const int* __restrict__ rs,
                                              int* __restrict__ cursor,
                                              int* __restrict__ csr) {
    int e = blockIdx.x * 256 + threadIdx.x;
    if (e < EE) {
        int r = erow[e];
        int p = atomicAdd(&cursor[r], 1);
        csr[rs[r] + p] = ecol[e];
    }
}

// ---------- canonicalize neighbor order (determinism across replays) ----------
__global__ __launch_bounds__(256) void k_sortwave(const int* __restrict__ rs,
                                                  int* __restrict__ csr) {
    int wid = (blockIdx.x * 256 + threadIdx.x) >> 6;   // one wave per row
    int l = threadIdx.x & 63;
    if (wid >= NN) return;
    int s0 = rs[wid], e0 = rs[wid + 1];
    int deg = e0 - s0;
    if (deg <= 1) return;
    if (deg <= 64) {
        int v = (l < deg) ? csr[s0 + l] : 0x7fffffff;
        int rank = 0;
#pragma unroll 8
        for (int m = 0; m < 64; ++m) {
            int vm = __shfl(v, m);
            bool less = (vm < v) || (vm == v && m < l);
            rank += (m < deg && less) ? 1 : 0;
        }
        if (l < deg) csr[s0 + rank] = v;
    } else if (l == 0) {                    // vanishingly rare fallback
        for (int i = s0 + 1; i < e0; ++i) {
            int v = csr[i];
            int j = i - 1;
            while (j >= s0 && csr[j] > v) { csr[j + 1] = csr[j]; --j; }
            csr[j + 1] = v;
        }
    }
}

// ---------- codebook normalize (144 rows of 128) ----------
__global__ __launch_bounds__(128) void k_cbnorm(const float* __restrict__ cb,
                                                float* __restrict__ cbn) {
    __shared__ float s[128];
    int row = blockIdx.x;                 // (layer*3+q)*16 + k
    int tid = threadIdx.x;
    float v = cb[row * DD + tid];
    s[tid] = v * v;
    __syncthreads();
    for (int o = 64; o > 0; o >>= 1) {
        if (tid < o) s[tid] += s[tid + o];
        __syncthreads();
    }
    float inv = 1.0f / (sqrtf(s[0]) + 1e-12f);
    cbn[(size_t)row * PADK + tid] = v * inv;
}

// ---------- input linear: h = x @ w + b (LDS-staged w, 4x4 register tile) ----
// Per-output accumulation: same operand values in the same ascending-k order
// as the previous (passing) gemm -> bit-identical h.
__global__ __launch_bounds__(256) void k_gemm(const float* __restrict__ x,
                                              const float* __restrict__ w,
                                              const float* __restrict__ bias,
                                              float* __restrict__ h) {
    __shared__ float wls[64][DD];   // 32 KiB (one k-chunk of w)
    __shared__ float xs[32][DD];    // 16 KiB
    int tid = threadIdx.x;
    int rbase = blockIdx.x * 32;
    int cg = tid & 31;              // col group (4 cols)
    int rg = tid >> 5;              // row group (4 rows)

#pragma unroll
    for (int p = 0; p < 4; ++p) {   // stage x tile: 32x128
        int i = p * 256 + tid;
        int r = i >> 5, c = (i & 31) * 4;
        *(float4*)&xs[r][c] = *(const float4*)&x[(size_t)(rbase + r) * DD + c];
    }

    float4 acc[4];
#pragma unroll
    for (int i = 0; i < 4; ++i) acc[i] = make_float4(0.f, 0.f, 0.f, 0.f);

    for (int chunk = 0; chunk < 2; ++chunk) {
        __syncthreads();            // xs visible (chunk 0) / wls reads done (chunk 1)
#pragma unroll
        for (int p = 0; p < 8; ++p) {   // stage w chunk: 64x128
            int i = p * 256 + tid;
            int kr = i >> 5, c = (i & 31) * 4;
            *(float4*)&wls[kr][c] = *(const float4*)&w[(size_t)(chunk * 64 + kr) * DD + c];
        }
        __syncthreads();
#pragma unroll 4
        for (int kk = 0; kk < 64; ++kk) {
            float4 wv = *(const float4*)&wls[kk][cg * 4];
            int k = chunk * 64 + kk;
#pragma unroll
            for (int i = 0; i < 4; ++i) {
                float xv = xs[rg * 4 + i][k];
                acc[i].x += xv * wv.x; acc[i].y += xv * wv.y;
                acc[i].z += xv * wv.z; acc[i].w += xv * wv.w;
            }
        }
    }

    float4 bv = *(const float4*)&bias[cg * 4];
#pragma unroll
    for (int i = 0; i < 4; ++i) {
        float4 o;
        o.x = acc[i].x + bv.x; o.y = acc[i].y + bv.y;
        o.z = acc[i].z + bv.z; o.w = acc[i].w + bv.w;
        *(float4*)&h[(size_t)(rbase + rg * 4 + i) * DD + cg * 4] = o;
    }
}

// ---------- SpMM: agg[r] = sum_{c in neigh(r)} norm[c]*h[c] ----------
__global__ __launch_bounds__(256) void k_spmm(const float* __restrict__ h,
                                              const float* __restrict__ normf,
                                              const int* __restrict__ rs,
                                              const int* __restrict__ csr,
                                              float* __restrict__ agg) {
    int lane = threadIdx.x & 31;
    int slot = threadIdx.x >> 5;
    int r = blockIdx.x * 8 + slot;
    int s0 = rs[r], e0 = rs[r + 1];
    int off = lane << 2;

    float ax = 0.f, ay = 0.f, az = 0.f, aw = 0.f;
    int j = s0;
    for (; j + 4 <= e0; j += 4) {
        int c0 = csr[j], c1 = csr[j + 1], c2 = csr[j + 2], c3 = csr[j + 3];
        float n0 = normf[c0], n1 = normf[c1], n2 = normf[c2], n3 = normf[c3];
        float4 v0 = *(const float4*)&h[(size_t)c0 * DD + off];
        float4 v1 = *(const float4*)&h[(size_t)c1 * DD + off];
        float4 v2 = *(const float4*)&h[(size_t)c2 * DD + off];
        float4 v3 = *(const float4*)&h[(size_t)c3 * DD + off];
        ax += n0 * v0.x; ax += n1 * v1.x; ax += n2 * v2.x; ax += n3 * v3.x;
        ay += n0 * v0.y; ay += n1 * v1.y; ay += n2 * v2.y; ay += n3 * v3.y;
        az += n0 * v0.z; az += n1 * v1.z; az += n2 * v2.z; az += n3 * v3.z;
        aw += n0 * v0.w; aw += n1 * v1.w; aw += n2 * v2.w; aw += n3 * v3.w;
    }
    for (; j < e0; ++j) {
        int c = csr[j];
        float ns = normf[c];
        float4 v = *(const float4*)&h[(size_t)c * DD + off];
        ax += ns * v.x;
        ay += ns * v.y;
        az += ns * v.z;
        aw += ns * v.w;
    }
    float4 o = {ax, ay, az, aw};
    *(float4*)&agg[(size_t)r * DD + off] = o;
}

// ---------- fused: x1 = norm*(agg + norm*h); residual VQ; h += x1 ----------
__global__ __launch_bounds__(256) void k_fused(const float* __restrict__ agg,
                                               float* __restrict__ h,
                                               const float* __restrict__ normf,
                                               const float* __restrict__ cbn_layer,
                                               float* __restrict__ idsf,
                                               float* __restrict__ lpart,
                                               int layer) {
    __shared__ float cb_s[NQ * KK * PADK];   // 25,344 B
    __shared__ float resid_s[4][DD];
    __shared__ float wsum[4];
    int tid = threadIdx.x;

    {
        const float4* src = (const float4*)cbn_layer;
        float4* dst = (float4*)cb_s;
        for (int i = tid; i < NQ * KK * PADK / 4; i += 256) dst[i] = src[i];
    }
    __syncthreads();

    int w = tid >> 6;      // wave id
    int l = tid & 63;      // lane
    int kq = l >> 2;       // codebook entry this lane helps with
    int sq = l & 3;        // 32-dim slice
    float lsum = 0.f;

    for (int it = 0; it < ROWS_PER_FBLOCK / 4; ++it) {
        int r = blockIdx.x * ROWS_PER_FBLOCK + it * 4 + w;

        float nr = normf[r];
        float2 hv = *(const float2*)&h[(size_t)r * DD + 2 * l];
        float2 av = *(const float2*)&agg[(size_t)r * DD + 2 * l];
        float x0 = nr * (av.x + nr * hv.x);
        float x1 = nr * (av.y + nr * hv.y);
        float r0 = x0, r1 = x1;

        for (int q = 0; q < NQ; ++q) {
            *(float2*)&resid_s[w][2 * l] = make_float2(r0, r1);
            __syncthreads();

            const float* cbq = &cb_s[(q * KK + kq) * PADK];
            const float* rsd = resid_s[w];
            float pd = 0.f;
#pragma unroll
            for (int i = 0; i < 8; ++i) {
                float4 cv = *(const float4*)&cbq[sq * 32 + i * 4];
                float4 rv = *(const float4*)&rsd[sq * 32 + i * 4];
                pd += cv.x * rv.x + cv.y * rv.y + cv.z * rv.z + cv.w * rv.w;
            }
            pd += __shfl_xor(pd, 1);
            pd += __shfl_xor(pd, 2);   // full dot(resid, cbn[kq]) in each quad

            float best = pd;
            int bk = kq;
            for (int m = 4; m < 64; m <<= 1) {
                float ov = __shfl_xor(best, m);
                int oi = __shfl_xor(bk, m);
                if (ov > best || (ov == best && oi < bk)) { best = ov; bk = oi; }
            }
            // bk = argmax (min index on tie), agreed by all lanes

            const float* cbk = &cb_s[(q * KK + bk) * PADK];
            float2 cv = *(const float2*)&cbk[2 * l];
            r0 -= cv.x;
            r1 -= cv.y;
            lsum += r0 * r0 + r1 * r1;

            if (l == 0) idsf[(size_t)r * (NL * NQ) + layer * NQ + q] = (float)bk;
            __syncthreads();
        }

        *(float2*)&h[(size_t)r * DD + 2 * l] = make_float2(x0 + hv.x, x1 + hv.y);
    }

    // block loss partial (deterministic)
#pragma unroll
    for (int m = 1; m < 64; m <<= 1) lsum += __shfl_xor(lsum, m);
    if (l == 0) wsum[w] = lsum;
    __syncthreads();
    if (tid == 0) {
        float tot = wsum[0] + wsum[1] + wsum[2] + wsum[3];
        lpart[layer * FUSED_BLOCKS + blockIdx.x] = tot * (0.25f / (float)(NN * DD));
    }
}

__global__ __launch_bounds__(256) void k_loss_reduce(const float* __restrict__ part,
                                                     float* __restrict__ out_loss) {
    __shared__ float s[256];
    float a = 0.f;
    for (int i = threadIdx.x; i < LPART_COUNT; i += 256) a += part[i];
    s[threadIdx.x] = a;
    __syncthreads();
    for (int o = 128; o > 0; o >>= 1) {
        if (threadIdx.x < o) s[threadIdx.x] += s[threadIdx.x + o];
        __syncthreads();
    }
    if (threadIdx.x == 0) out_loss[0] = s[0];
}

extern "C" void kernel_launch(void* const* d_in, const int* in_sizes, int n_in,
                              void* d_out, int out_size, void* d_ws, size_t ws_size,
                              hipStream_t stream) {
    if (ws_size < WS_NEEDED) return;

    const float* x    = (const float*)d_in[0];
    const float* w_in = (const float*)d_in[1];
    const float* b_in = (const float*)d_in[2];
    const float* cbs  = (const float*)d_in[3];
    const int*   erow = (const int*)d_in[4];
    const int*   ecol = (const int*)d_in[5];

    float* out  = (float*)d_out;
    float* hbuf = out;                                   // [N][D] working h = output 0
    float* loss = out + (size_t)NN * DD;                 // scalar output 1
    float* idsf = out + (size_t)NN * DD + 1;             // [N][9] output 2 (as float)

    char* ws = (char*)d_ws;
    float* agg    = (float*)(ws + OFF_AGG);
    int*   csr    = (int*)(ws + OFF_CSR);
    float* cbn    = (float*)(ws + OFF_CBN);
    float* normf  = (float*)(ws + OFF_NORM);
    int*   deg    = (int*)(ws + OFF_DEG);
    int*   cursor = (int*)(ws + OFF_CUR);
    int*   rs     = (int*)(ws + OFF_RS);
    int*   bsum   = (int*)(ws + OFF_BSUM);
    float* lpart  = (float*)(ws + OFF_LPART);

    // zero deg + cursor (contiguous)
    hipMemsetAsync(ws + OFF_DEG, 0, 800000, stream);

    const int NB_E  = (EE + 255) / 256;      // 6250
    const int NB_SC = (NN + 1023) / 1024;    // 98
    const int NB_W  = (NN + 3) / 4;          // 25000 (4 waves/block)

    k_count<<<NB_E, 256, 0, stream>>>(erow, deg);
    k_scan1<<<NB_SC, 1024, 0, stream>>>(deg, rs, bsum);
    k_scan2<<<1, 128, 0, stream>>>(bsum, NB_SC);
    k_scan3<<<NB_SC, 1024, 0, stream>>>(deg, rs, bsum, normf);
    k_fill<<<NB_E, 256, 0, stream>>>(erow, ecol, rs, cursor, csr);
    k_sortwave<<<NB_W, 256, 0, stream>>>(rs, csr);

    k_cbnorm<<<NL * NQ * KK, 128, 0, stream>>>(cbs, cbn);
    k_gemm<<<NN / 32, 256, 0, stream>>>(x, w_in, b_in, hbuf);

    for (int layer = 0; layer < NL; ++layer) {
        k_spmm<<<NN / 8, 256, 0, stream>>>(hbuf, normf, rs, csr, agg);
        k_fused<<<FUSED_BLOCKS, 256, 0, stream>>>(agg, hbuf, normf,
                                                  cbn + (size_t)layer * NQ * KK * PADK,
                                                  idsf, lpart, layer);
    }

    k_loss_reduce<<<1, 256, 0, stream>>>(lpart, loss);
}

// Round 7
// 913.131 us; speedup vs baseline: 1.9023x; 1.1177x over previous
//
#include <hip/hip_runtime.h>

#define NN 100000
#define EE 1600000
#define DD 128
#define NL 3
#define NQ 3
#define KK 16
#define ROWS_PER_FBLOCK 32
#define FUSED_BLOCKS (NN / ROWS_PER_FBLOCK)      // 3125
#define LPART_COUNT (NL * FUSED_BLOCKS)

// permuted codebook layout (words): entry k, dim = sq*32 + i*4 + d  lives at
//   (layer*NQ + q)*QSTRIDE + i*ISTRIDE + k*16 + sq*4 + d
// so the dot-read for lane l (= kq*4+sq) is a linear float4 at i*ISTRIDE + l*4.
#define ISTRIDE 260                  // 64 lanes*4 words + 4 pad (bank shear)
#define QSTRIDE (8 * ISTRIDE)        // 2080 words per (layer,q)
#define LAYER_CBN (NQ * QSTRIDE)     // 6240 words per layer
// resid layout (words): dim = s*32 + j -> s*RSTRIDE + j
#define RSTRIDE 36
#define RBUF 144                     // 3*36+32 rounded; keeps rows 16B aligned

// ---- workspace layout (bytes) ----
static constexpr size_t OFF_AGG   = 0;          // N*D f32       = 51,200,000
static constexpr size_t OFF_CSR   = 51200000;   // E   i32       =  6,400,000
static constexpr size_t OFF_CBN   = 57600000;   // 9*2080 f32    =     74,880
static constexpr size_t OFF_NORM  = 57904128;   // N   f32       =    400,000
static constexpr size_t OFF_DEG   = 58304128;   // N   i32       =    400,000
static constexpr size_t OFF_CUR   = 58704128;   // N   i32       =    400,000
static constexpr size_t OFF_RS    = 59104128;   // (N+1) i32     =    400,004
static constexpr size_t OFF_BSUM  = 59504640;   // 128 i32
static constexpr size_t OFF_LPART = 59505152;   // NL*3125 f32
static constexpr size_t WS_NEEDED = 59805152;

// ---------- CSR build ----------
__global__ __launch_bounds__(256) void k_count(const int* __restrict__ erow,
                                               int* __restrict__ deg) {
    int e = blockIdx.x * 256 + threadIdx.x;
    if (e < EE) atomicAdd(&deg[erow[e]], 1);
}

__global__ __launch_bounds__(1024) void k_scan1(const int* __restrict__ deg,
                                                int* __restrict__ rs,
                                                int* __restrict__ bsum) {
    __shared__ int s[1024];
    int tid = threadIdx.x;
    int idx = blockIdx.x * 1024 + tid;
    int v = (idx < NN) ? deg[idx] : 0;
    s[tid] = v;
    __syncthreads();
    for (int o = 1; o < 1024; o <<= 1) {
        int t2 = s[tid];
        if (tid >= o) t2 += s[tid - o];
        __syncthreads();
        s[tid] = t2;
        __syncthreads();
    }
    if (idx < NN) rs[idx] = s[tid] - v;       // exclusive
    if (tid == 1023) bsum[blockIdx.x] = s[1023];
}

__global__ __launch_bounds__(128) void k_scan2(int* __restrict__ bsum, int nb) {
    __shared__ int s[128];
    int tid = threadIdx.x;
    int v = (tid < nb) ? bsum[tid] : 0;
    s[tid] = v;
    __syncthreads();
    for (int o = 1; o < 128; o <<= 1) {
        int t2 = s[tid];
        if (tid >= o) t2 += s[tid - o];
        __syncthreads();
        s[tid] = t2;
        __syncthreads();
    }
    if (tid < nb) bsum[tid] = s[tid] - v;     // exclusive
}

__global__ __launch_bounds__(1024) void k_scan3(const int* __restrict__ deg,
                                                int* __restrict__ rs,
                                                const int* __restrict__ bsum,
                                                float* __restrict__ normf) {
    int idx = blockIdx.x * 1024 + threadIdx.x;
    if (idx < NN) {
        rs[idx] += bsum[blockIdx.x];
        normf[idx] = rsqrtf(1.0f + (float)deg[idx]);
    }
    if (idx == 0) rs[NN] = EE;
}

__global__ __launch_bounds__(256) void k_fill(const int* __restrict__ erow,
                                              const int* __restrict__ ecol,
                                              const int* __restrict__ rs,
                                              int* __restrict__ cursor,
                                              int* __restrict__ csr) {
    int e = blockIdx.x * 256 + threadIdx.x;
    if (e < EE) {
        int r = erow[e];
        int p = atomicAdd(&cursor[r], 1);
        csr[rs[r] + p] = ecol[e];
    }
}

// ---------- canonicalize neighbor order (determinism across replays) ----------
__global__ __launch_bounds__(256) void k_sortwave(const int* __restrict__ rs,
                                                  int* __restrict__ csr) {
    int wid = (blockIdx.x * 256 + threadIdx.x) >> 6;   // one wave per row
    int l = threadIdx.x & 63;
    if (wid >= NN) return;
    int s0 = rs[wid], e0 = rs[wid + 1];
    int deg = e0 - s0;
    if (deg <= 1) return;
    if (deg <= 64) {
        int v = (l < deg) ? csr[s0 + l] : 0x7fffffff;
        int rank = 0;
#pragma unroll 8
        for (int m = 0; m < 64; ++m) {
            int vm = __shfl(v, m);
            bool less = (vm < v) || (vm == v && m < l);
            rank += (m < deg && less) ? 1 : 0;
        }
        if (l < deg) csr[s0 + rank] = v;
    } else if (l == 0) {                    // vanishingly rare fallback
        for (int i = s0 + 1; i < e0; ++i) {
            int v = csr[i];
            int j = i - 1;
            while (j >= s0 && csr[j] > v) { csr[j + 1] = csr[j]; --j; }
            csr[j + 1] = v;
        }
    }
}

// ---------- codebook normalize -> permuted layout ----------
__global__ __launch_bounds__(128) void k_cbnorm(const float* __restrict__ cb,
                                                float* __restrict__ cbn) {
    __shared__ float s[128];
    int row = blockIdx.x;                 // (layer*NQ + q)*KK + k
    int tid = threadIdx.x;
    float v = cb[row * DD + tid];
    s[tid] = v * v;
    __syncthreads();
    for (int o = 64; o > 0; o >>= 1) {
        if (tid < o) s[tid] += s[tid + o];
        __syncthreads();
    }
    float inv = 1.0f / (sqrtf(s[0]) + 1e-12f);
    int lq = row >> 4;                    // layer*NQ + q  (0..8)
    int k  = row & 15;
    int sq = tid >> 5, ii = (tid >> 2) & 7, d = tid & 3;
    cbn[(size_t)lq * QSTRIDE + ii * ISTRIDE + k * 16 + sq * 4 + d] = v * inv;
}

// ---------- input linear: h = x @ w + b (LDS-staged w, 4x4 register tile) ----
__global__ __launch_bounds__(256) void k_gemm(const float* __restrict__ x,
                                              const float* __restrict__ w,
                                              const float* __restrict__ bias,
                                              float* __restrict__ h) {
    __shared__ float wls[64][DD];   // 32 KiB (one k-chunk of w)
    __shared__ float xs[32][DD];    // 16 KiB
    int tid = threadIdx.x;
    int rbase = blockIdx.x * 32;
    int cg = tid & 31;              // col group (4 cols)
    int rg = tid >> 5;              // row group (4 rows)

#pragma unroll
    for (int p = 0; p < 4; ++p) {   // stage x tile: 32x128
        int i = p * 256 + tid;
        int r = i >> 5, c = (i & 31) * 4;
        *(float4*)&xs[r][c] = *(const float4*)&x[(size_t)(rbase + r) * DD + c];
    }

    float4 acc[4];
#pragma unroll
    for (int i = 0; i < 4; ++i) acc[i] = make_float4(0.f, 0.f, 0.f, 0.f);

    for (int chunk = 0; chunk < 2; ++chunk) {
        __syncthreads();
#pragma unroll
        for (int p = 0; p < 8; ++p) {   // stage w chunk: 64x128
            int i = p * 256 + tid;
            int kr = i >> 5, c = (i & 31) * 4;
            *(float4*)&wls[kr][c] = *(const float4*)&w[(size_t)(chunk * 64 + kr) * DD + c];
        }
        __syncthreads();
#pragma unroll 4
        for (int kk = 0; kk < 64; ++kk) {
            float4 wv = *(const float4*)&wls[kk][cg * 4];
            int k = chunk * 64 + kk;
#pragma unroll
            for (int i = 0; i < 4; ++i) {
                float xv = xs[rg * 4 + i][k];
                acc[i].x += xv * wv.x; acc[i].y += xv * wv.y;
                acc[i].z += xv * wv.z; acc[i].w += xv * wv.w;
            }
        }
    }

    float4 bv = *(const float4*)&bias[cg * 4];
#pragma unroll
    for (int i = 0; i < 4; ++i) {
        float4 o;
        o.x = acc[i].x + bv.x; o.y = acc[i].y + bv.y;
        o.z = acc[i].z + bv.z; o.w = acc[i].w + bv.w;
        *(float4*)&h[(size_t)(rbase + rg * 4 + i) * DD + cg * 4] = o;
    }
}

// ---------- SpMM: agg[r] = sum_{c in neigh(r)} norm[c]*h[c] ----------
// 32 lanes per row (float4 each), 8 rows per 256-block, unroll-by-8 MLP.
// Per-dim adds stay ascending-j separate statements -> bit-identical agg.
__global__ __launch_bounds__(256) void k_spmm(const float* __restrict__ h,
                                              const float* __restrict__ normf,
                                              const int* __restrict__ rs,
                                              const int* __restrict__ csr,
                                              float* __restrict__ agg) {
    int lane = threadIdx.x & 31;
    int slot = threadIdx.x >> 5;
    int r = blockIdx.x * 8 + slot;
    int s0 = rs[r], e0 = rs[r + 1];
    int off = lane << 2;

    float ax = 0.f, ay = 0.f, az = 0.f, aw = 0.f;
    int j = s0;
    for (; j + 8 <= e0; j += 8) {
        int c0 = csr[j],     c1 = csr[j + 1], c2 = csr[j + 2], c3 = csr[j + 3];
        int c4 = csr[j + 4], c5 = csr[j + 5], c6 = csr[j + 6], c7 = csr[j + 7];
        float n0 = normf[c0], n1 = normf[c1], n2 = normf[c2], n3 = normf[c3];
        float n4 = normf[c4], n5 = normf[c5], n6 = normf[c6], n7 = normf[c7];
        float4 v0 = *(const float4*)&h[(size_t)c0 * DD + off];
        float4 v1 = *(const float4*)&h[(size_t)c1 * DD + off];
        float4 v2 = *(const float4*)&h[(size_t)c2 * DD + off];
        float4 v3 = *(const float4*)&h[(size_t)c3 * DD + off];
        float4 v4 = *(const float4*)&h[(size_t)c4 * DD + off];
        float4 v5 = *(const float4*)&h[(size_t)c5 * DD + off];
        float4 v6 = *(const float4*)&h[(size_t)c6 * DD + off];
        float4 v7 = *(const float4*)&h[(size_t)c7 * DD + off];
        ax += n0 * v0.x; ax += n1 * v1.x; ax += n2 * v2.x; ax += n3 * v3.x;
        ax += n4 * v4.x; ax += n5 * v5.x; ax += n6 * v6.x; ax += n7 * v7.x;
        ay += n0 * v0.y; ay += n1 * v1.y; ay += n2 * v2.y; ay += n3 * v3.y;
        ay += n4 * v4.y; ay += n5 * v5.y; ay += n6 * v6.y; ay += n7 * v7.y;
        az += n0 * v0.z; az += n1 * v1.z; az += n2 * v2.z; az += n3 * v3.z;
        az += n4 * v4.z; az += n5 * v5.z; az += n6 * v6.z; az += n7 * v7.z;
        aw += n0 * v0.w; aw += n1 * v1.w; aw += n2 * v2.w; aw += n3 * v3.w;
        aw += n4 * v4.w; aw += n5 * v5.w; aw += n6 * v6.w; aw += n7 * v7.w;
    }
    for (; j + 4 <= e0; j += 4) {
        int c0 = csr[j], c1 = csr[j + 1], c2 = csr[j + 2], c3 = csr[j + 3];
        float n0 = normf[c0], n1 = normf[c1], n2 = normf[c2], n3 = normf[c3];
        float4 v0 = *(const float4*)&h[(size_t)c0 * DD + off];
        float4 v1 = *(const float4*)&h[(size_t)c1 * DD + off];
        float4 v2 = *(const float4*)&h[(size_t)c2 * DD + off];
        float4 v3 = *(const float4*)&h[(size_t)c3 * DD + off];
        ax += n0 * v0.x; ax += n1 * v1.x; ax += n2 * v2.x; ax += n3 * v3.x;
        ay += n0 * v0.y; ay += n1 * v1.y; ay += n2 * v2.y; ay += n3 * v3.y;
        az += n0 * v0.z; az += n1 * v1.z; az += n2 * v2.z; az += n3 * v3.z;
        aw += n0 * v0.w; aw += n1 * v1.w; aw += n2 * v2.w; aw += n3 * v3.w;
    }
    for (; j < e0; ++j) {
        int c = csr[j];
        float ns = normf[c];
        float4 v = *(const float4*)&h[(size_t)c * DD + off];
        ax += ns * v.x;
        ay += ns * v.y;
        az += ns * v.z;
        aw += ns * v.w;
    }
    float4 o = {ax, ay, az, aw};
    *(float4*)&agg[(size_t)r * DD + off] = o;
}

// ---------- fused: x1 = norm*(agg + norm*h); residual VQ; h += x1 ----------
// Conflict-free LDS layouts; values/order identical to the passing kernel.
__global__ __launch_bounds__(256) void k_fused(const float* __restrict__ agg,
                                               float* __restrict__ h,
                                               const float* __restrict__ normf,
                                               const float* __restrict__ cbn_layer,
                                               float* __restrict__ idsf,
                                               float* __restrict__ lpart,
                                               int layer) {
    __shared__ float cb_s[LAYER_CBN];        // 24,960 B (permuted layout)
    __shared__ float resid_s[4][RBUF];       // padded resid (stride 36/slice)
    __shared__ float wsum[4];
    int tid = threadIdx.x;

    {   // linear copy: global cbn is already in the permuted layout
        const float4* src = (const float4*)cbn_layer;
        float4* dst = (float4*)cb_s;
        for (int t = tid; t < LAYER_CBN / 4; t += 256) dst[t] = src[t];
    }
    __syncthreads();

    int w = tid >> 6;      // wave id
    int l = tid & 63;      // lane
    int rwrd = (l >> 4) * RSTRIDE + ((2 * l) & 31);           // resid write word
    int sq = l & 3;                                            // resid read slice
    int cb2 = ((l >> 1) & 7) * ISTRIDE + (l >> 4) * 4 + 2 * (l & 1); // cb[?][2l] word
    float lsum = 0.f;

    for (int it = 0; it < ROWS_PER_FBLOCK / 4; ++it) {
        int r = blockIdx.x * ROWS_PER_FBLOCK + it * 4 + w;

        float nr = normf[r];
        float2 hv = *(const float2*)&h[(size_t)r * DD + 2 * l];
        float2 av = *(const float2*)&agg[(size_t)r * DD + 2 * l];
        float x0 = nr * (av.x + nr * hv.x);
        float x1 = nr * (av.y + nr * hv.y);
        float r0 = x0, r1 = x1;

        for (int q = 0; q < NQ; ++q) {
            *(float2*)&resid_s[w][rwrd] = make_float2(r0, r1);
            __syncthreads();

            const float* cbq = &cb_s[q * QSTRIDE];
            const float* rsd = resid_s[w];
            float pd = 0.f;
#pragma unroll
            for (int i = 0; i < 8; ++i) {
                float4 cv = *(const float4*)&cbq[i * ISTRIDE + l * 4];
                float4 rv = *(const float4*)&rsd[sq * RSTRIDE + i * 4];
                pd += cv.x * rv.x + cv.y * rv.y + cv.z * rv.z + cv.w * rv.w;
            }
            pd += __shfl_xor(pd, 1);
            pd += __shfl_xor(pd, 2);   // full dot(resid, cbn[kq]) in each quad

            float best = pd;
            int bk = l >> 2;
            for (int m = 4; m < 64; m <<= 1) {
                float ov = __shfl_xor(best, m);
                int oi = __shfl_xor(bk, m);
                if (ov > best || (ov == best && oi < bk)) { best = ov; bk = oi; }
            }
            // bk = argmax (min index on tie), agreed by all lanes

            float2 cv2 = *(const float2*)&cb_s[q * QSTRIDE + bk * 16 + cb2];
            r0 -= cv2.x;
            r1 -= cv2.y;
            lsum += r0 * r0 + r1 * r1;

            if (l == 0) idsf[(size_t)r * (NL * NQ) + layer * NQ + q] = (float)bk;
            __syncthreads();
        }

        *(float2*)&h[(size_t)r * DD + 2 * l] = make_float2(x0 + hv.x, x1 + hv.y);
    }

    // block loss partial (deterministic)
#pragma unroll
    for (int m = 1; m < 64; m <<= 1) lsum += __shfl_xor(lsum, m);
    if (l == 0) wsum[w] = lsum;
    __syncthreads();
    if (tid == 0) {
        float tot = wsum[0] + wsum[1] + wsum[2] + wsum[3];
        lpart[layer * FUSED_BLOCKS + blockIdx.x] = tot * (0.25f / (float)(NN * DD));
    }
}

__global__ __launch_bounds__(256) void k_loss_reduce(const float* __restrict__ part,
                                                     float* __restrict__ out_loss) {
    __shared__ float s[256];
    float a = 0.f;
    for (int i = threadIdx.x; i < LPART_COUNT; i += 256) a += part[i];
    s[threadIdx.x] = a;
    __syncthreads();
    for (int o = 128; o > 0; o >>= 1) {
        if (threadIdx.x < o) s[threadIdx.x] += s[threadIdx.x + o];
        __syncthreads();
    }
    if (threadIdx.x == 0) out_loss[0] = s[0];
}

extern "C" void kernel_launch(void* const* d_in, const int* in_sizes, int n_in,
                              void* d_out, int out_size, void* d_ws, size_t ws_size,
                              hipStream_t stream) {
    if (ws_size < WS_NEEDED) return;

    const float* x    = (const float*)d_in[0];
    const float* w_in = (const float*)d_in[1];
    const float* b_in = (const float*)d_in[2];
    const float* cbs  = (const float*)d_in[3];
    const int*   erow = (const int*)d_in[4];
    const int*   ecol = (const int*)d_in[5];

    float* out  = (float*)d_out;
    float* hbuf = out;                                   // [N][D] working h = output 0
    float* loss = out + (size_t)NN * DD;                 // scalar output 1
    float* idsf = out + (size_t)NN * DD + 1;             // [N][9] output 2 (as float)

    char* ws = (char*)d_ws;
    float* agg    = (float*)(ws + OFF_AGG);
    int*   csr    = (int*)(ws + OFF_CSR);
    float* cbn    = (float*)(ws + OFF_CBN);
    float* normf  = (float*)(ws + OFF_NORM);
    int*   deg    = (int*)(ws + OFF_DEG);
    int*   cursor = (int*)(ws + OFF_CUR);
    int*   rs     = (int*)(ws + OFF_RS);
    int*   bsum   = (int*)(ws + OFF_BSUM);
    float* lpart  = (float*)(ws + OFF_LPART);

    // zero deg + cursor (contiguous)
    hipMemsetAsync(ws + OFF_DEG, 0, 800000, stream);

    const int NB_E  = (EE + 255) / 256;      // 6250
    const int NB_SC = (NN + 1023) / 1024;    // 98
    const int NB_W  = (NN + 3) / 4;          // 25000 (4 waves/block)

    k_count<<<NB_E, 256, 0, stream>>>(erow, deg);
    k_scan1<<<NB_SC, 1024, 0, stream>>>(deg, rs, bsum);
    k_scan2<<<1, 128, 0, stream>>>(bsum, NB_SC);
    k_scan3<<<NB_SC, 1024, 0, stream>>>(deg, rs, bsum, normf);
    k_fill<<<NB_E, 256, 0, stream>>>(erow, ecol, rs, cursor, csr);
    k_sortwave<<<NB_W, 256, 0, stream>>>(rs, csr);

    k_cbnorm<<<NL * NQ * KK, 128, 0, stream>>>(cbs, cbn);
    k_gemm<<<NN / 32, 256, 0, stream>>>(x, w_in, b_in, hbuf);

    for (int layer = 0; layer < NL; ++layer) {
        k_spmm<<<NN / 8, 256, 0, stream>>>(hbuf, normf, rs, csr, agg);
        k_fused<<<FUSED_BLOCKS, 256, 0, stream>>>(agg, hbuf, normf,
                                                  cbn + (size_t)layer * LAYER_CBN,
                                                  idsf, lpart, layer);
    }

    k_loss_reduce<<<1, 256, 0, stream>>>(lpart, loss);
}